// Round 8
// baseline (372.892 us; speedup 1.0000x reference)
//
#include <hip/hip_runtime.h>

#define N_NODESC 50000
#define N_EDGESC 800000
#define NFEATC 128
#define NHIDC 64
#define NHEADC 4
#define NBASEC 8
#define NCLASSC 40
#define HD1C (NHEADC * NHIDC)        // 256
#define W1TROWS 320                  // 256 + 8, padded to 64-multiple
#define W2TROWS 64                   // 40 + 8, padded

typedef __attribute__((ext_vector_type(8))) short bf16x8;
typedef __attribute__((ext_vector_type(4))) float f32x4;

__device__ inline float bf2f(unsigned short u) {
  union { unsigned int i; float f; } v;
  v.i = ((unsigned int)u) << 16;
  return v.f;
}
__device__ inline float blo(unsigned int u) {
  union { unsigned int i; float f; } v; v.i = u << 16; return v.f;
}
__device__ inline float bhi(unsigned int u) {
  union { unsigned int i; float f; } v; v.i = u & 0xffff0000u; return v.f;
}
__device__ inline unsigned short f2bf(float x) {
  union { float f; unsigned int i; } v;
  v.f = x;
  unsigned int r = v.i + 0x7FFF + ((v.i >> 16) & 1);  // RNE
  return (unsigned short)(r >> 16);
}

// ======== layer-1 fused: [h1 | s1] = x @ [W1|B1] (MFMA, x staged in LDS once),
//          esrc1/edst1 computed in-epilogue from the s-columns ========
__global__ __launch_bounds__(256) void gemm1_fused(
    const float* __restrict__ x, const unsigned short* __restrict__ W1T,
    const float* __restrict__ cs1, const float* __restrict__ cd1,
    unsigned short* __restrict__ h1b, float* __restrict__ esrc, float* __restrict__ edst) {
  __shared__ unsigned short As[256 * 132];
  __shared__ float sS[256 * 8];
  const int tid = threadIdx.x;
  const int wave = tid >> 6, lane = tid & 63;
  const int row0 = blockIdx.x * 256;

#pragma unroll
  for (int p = 0; p < 32; ++p) {
    const int g4 = p * 256 + tid;
    const int r = g4 >> 5;
    const int k4 = g4 & 31;
    int grow = row0 + r;
    grow = grow < N_NODESC ? grow : N_NODESC - 1;
    const float4 v = *reinterpret_cast<const float4*>(x + (size_t)grow * NFEATC + k4 * 4);
    ushort4 o;
    o.x = f2bf(v.x); o.y = f2bf(v.y); o.z = f2bf(v.z); o.w = f2bf(v.w);
    *reinterpret_cast<ushort4*>(&As[r * 132 + k4 * 4]) = o;
  }
  __syncthreads();

  const int lm = lane & 15, q = lane >> 4, kq = q * 8;
  for (int t = 0; t < 5; ++t) {
    const int n0 = t * 64;
    f32x4 acc[4][4] = {};
#pragma unroll
    for (int k0 = 0; k0 < NFEATC; k0 += 32) {
      bf16x8 af[4], bfr[4];
#pragma unroll
      for (int mi = 0; mi < 4; ++mi)
        af[mi] = *reinterpret_cast<const bf16x8*>(&As[(wave * 64 + mi * 16 + lm) * 132 + k0 + kq]);
#pragma unroll
      for (int ni = 0; ni < 4; ++ni)
        bfr[ni] = *reinterpret_cast<const bf16x8*>(W1T + (size_t)(n0 + ni * 16 + lm) * NFEATC + k0 + kq);
#pragma unroll
      for (int mi = 0; mi < 4; ++mi)
#pragma unroll
        for (int ni = 0; ni < 4; ++ni)
          acc[mi][ni] = __builtin_amdgcn_mfma_f32_16x16x32_bf16(af[mi], bfr[ni], acc[mi][ni],
                                                                0, 0, 0);
    }
    if (t < 4) {
#pragma unroll
      for (int mi = 0; mi < 4; ++mi)
#pragma unroll
        for (int r = 0; r < 4; ++r) {
          const int row = row0 + wave * 64 + mi * 16 + q * 4 + r;
          if (row >= N_NODESC) continue;
#pragma unroll
          for (int ni = 0; ni < 4; ++ni)
            h1b[(size_t)row * HD1C + n0 + ni * 16 + lm] = f2bf(acc[mi][ni][r]);
        }
    } else {
      if (lm < 8) {
#pragma unroll
        for (int mi = 0; mi < 4; ++mi)
#pragma unroll
          for (int r = 0; r < 4; ++r)
            sS[(wave * 64 + mi * 16 + q * 4 + r) * 8 + lm] = acc[mi][0][r];
      }
      const int rloc = wave * 64 + lane;
      const int grow = row0 + rloc;
      if (grow < N_NODESC) {
        float sb[8];
#pragma unroll
        for (int b = 0; b < 8; ++b) sb[b] = sS[rloc * 8 + b];
#pragma unroll
        for (int h = 0; h < NHEADC; ++h) {
          float a = 0.f, d = 0.f;
#pragma unroll
          for (int b = 0; b < NBASEC; ++b) {
            a += sb[b] * cs1[b * NHEADC + h];
            d += sb[b] * cd1[b * NHEADC + h];
          }
          esrc[grow * NHEADC + h] = a;
          edst[grow * NHEADC + h] = d;
        }
      }
    }
  }
}

// ======== layer-2 fused: [g2 | s2] = hact @ [W2|B2], esrc2/edst2 in-epilogue ========
__global__ __launch_bounds__(256) void gemm2_fused(
    const unsigned short* __restrict__ A, const unsigned short* __restrict__ W2T,
    const float* __restrict__ cs2, const float* __restrict__ cd2,
    unsigned short* __restrict__ g2b, float* __restrict__ esrc, float* __restrict__ edst) {
  __shared__ float sS[256 * 8];
  const int wave = threadIdx.x >> 6;
  const int lane = threadIdx.x & 63;
  const int m0 = blockIdx.x * 256 + wave * 64;
  const int lm = lane & 15, q = lane >> 4, kq = q * 8;
  f32x4 acc[4][4] = {};

  for (int k0 = 0; k0 < HD1C; k0 += 32) {
    bf16x8 af[4], bfr[4];
#pragma unroll
    for (int mi = 0; mi < 4; ++mi) {
      int row = m0 + mi * 16 + lm;
      row = row < N_NODESC ? row : N_NODESC - 1;
      af[mi] = *reinterpret_cast<const bf16x8*>(A + (size_t)row * HD1C + k0 + kq);
    }
#pragma unroll
    for (int ni = 0; ni < 4; ++ni)
      bfr[ni] = *reinterpret_cast<const bf16x8*>(W2T + (size_t)(ni * 16 + lm) * HD1C + k0 + kq);
#pragma unroll
    for (int mi = 0; mi < 4; ++mi)
#pragma unroll
      for (int ni = 0; ni < 4; ++ni)
        acc[mi][ni] = __builtin_amdgcn_mfma_f32_16x16x32_bf16(af[mi], bfr[ni], acc[mi][ni],
                                                              0, 0, 0);
  }
#pragma unroll
  for (int mi = 0; mi < 4; ++mi)
#pragma unroll
    for (int r = 0; r < 4; ++r) {
      const int row = m0 + mi * 16 + q * 4 + r;
      if (row >= N_NODESC) continue;
#pragma unroll
      for (int ni = 0; ni < 3; ++ni) {
        const int col = ni * 16 + lm;
        if (col < NCLASSC) g2b[(size_t)row * NCLASSC + col] = f2bf(acc[mi][ni][r]);
      }
    }
  if (lm >= 8) {
#pragma unroll
    for (int mi = 0; mi < 4; ++mi)
#pragma unroll
      for (int r = 0; r < 4; ++r)
        sS[(wave * 64 + mi * 16 + q * 4 + r) * 8 + (lm - 8)] = acc[mi][2][r];
  }
  const int rloc = wave * 64 + lane;
  const int grow = blockIdx.x * 256 + rloc;
  if (grow < N_NODESC) {
    float sb[8];
#pragma unroll
    for (int b = 0; b < 8; ++b) sb[b] = sS[rloc * 8 + b];
    float a = 0.f, d = 0.f;
#pragma unroll
    for (int b = 0; b < NBASEC; ++b) {
      a += sb[b] * cs2[b];
      d += sb[b] * cd2[b];
    }
    esrc[grow] = a;
    edst[grow] = d;
  }
}

// ---------------- fused prep: W1T | W2T | dst histogram ----------------
#define W1T_NB ((W1TROWS * NFEATC + 255) / 256)                 // 160
#define W2T_NB ((W2TROWS * HD1C + 255) / 256)                   // 64
#define HIST_NB ((N_EDGESC + 255) / 256)                        // 3125
#define PREP_NB (W1T_NB + W2T_NB + HIST_NB)

__global__ __launch_bounds__(256) void prep_kernel(
    const float* __restrict__ W1, const float* __restrict__ B1,
    unsigned short* __restrict__ W1T,
    const float* __restrict__ W2, const float* __restrict__ B2,
    unsigned short* __restrict__ W2T,
    const int* __restrict__ dst, int* __restrict__ counts) {
  int b = blockIdx.x;
  if (b < W1T_NB) {
    const int i = b * 256 + threadIdx.x;
    if (i < W1TROWS * NFEATC) {
      const int n = i / NFEATC, k = i - n * NFEATC;
      float v = 0.f;
      if (n < HD1C) v = W1[(size_t)k * HD1C + n];
      else if (n < HD1C + NBASEC) v = B1[(size_t)k * NBASEC + (n - HD1C)];
      W1T[i] = f2bf(v);
    }
    return;
  }
  b -= W1T_NB;
  if (b < W2T_NB) {
    const int i = b * 256 + threadIdx.x;
    if (i < W2TROWS * HD1C) {
      const int n = i / HD1C, k = i - n * HD1C;
      float v = 0.f;
      if (n < NCLASSC) v = W2[(size_t)k * NCLASSC + n];
      else if (n < NCLASSC + NBASEC) v = B2[(size_t)k * NBASEC + (n - NCLASSC)];
      W2T[i] = f2bf(v);
    }
    return;
  }
  b -= W2T_NB;
  {
    const int e = b * 256 + threadIdx.x;
    if (e < N_EDGESC) atomicAdd(&counts[dst[e]], 1);
  }
}

// ---------------- single-block scan: offsets = exclusive_scan(counts) ----------------
#define SCAN_CHUNK 49   // 1024 * 49 = 50176 >= 50000

__global__ __launch_bounds__(1024) void scan50k(const int* __restrict__ counts,
                                                int* __restrict__ offsets) {
  __shared__ int sm[1024];
  const int tid = threadIdx.x;
  const int base = tid * SCAN_CHUNK;
  int s = 0;
#pragma unroll
  for (int j = 0; j < SCAN_CHUNK; ++j) {
    const int idx = base + j;
    if (idx < N_NODESC) s += counts[idx];
  }
  sm[tid] = s;
  __syncthreads();
  for (int d = 1; d < 1024; d <<= 1) {
    const int t = (tid >= d) ? sm[tid - d] : 0;
    __syncthreads();
    sm[tid] += t;
    __syncthreads();
  }
  int run = sm[tid] - s;  // exclusive prefix of this thread's chunk
#pragma unroll
  for (int j = 0; j < SCAN_CHUNK; ++j) {
    const int idx = base + j;
    if (idx < N_NODESC) {
      offsets[idx] = run;
      run += counts[idx];
    }
  }
  if (tid == 0) offsets[N_NODESC] = N_EDGESC;
}

// -------- scatter + layer-1 edge-weight precompute: srcs_csr, w1[pos][h]=exp(leaky(e)) ----
__global__ void scatter_w1(const int* __restrict__ dst, const int* __restrict__ src,
                           const int* __restrict__ offsets, int* __restrict__ counts,
                           const float* __restrict__ esrc, const float* __restrict__ edst,
                           int* __restrict__ srcs_csr, float* __restrict__ w1) {
  const int e = blockIdx.x * blockDim.x + threadIdx.x;
  if (e >= N_EDGESC) return;
  const int n = dst[e];
  const int s = src[e];
  const int pos = offsets[n] + atomicSub(&counts[n], 1) - 1;
  srcs_csr[pos] = s;
  const float4 es = *reinterpret_cast<const float4*>(esrc + (size_t)s * NHEADC);
  const float4 ed = *reinterpret_cast<const float4*>(edst + (size_t)n * NHEADC);
  float4 w;
  float t;
  t = es.x + ed.x; t = t > 0.f ? t : 0.2f * t; w.x = __expf(t);
  t = es.y + ed.y; t = t > 0.f ? t : 0.2f * t; w.y = __expf(t);
  t = es.z + ed.z; t = t > 0.f ? t : 0.2f * t; w.z = __expf(t);
  t = es.w + ed.w; t = t > 0.f ? t : 0.2f * t; w.w = __expf(t);
  *reinterpret_cast<float4*>(w1 + (size_t)pos * NHEADC) = w;
}

// ---------- layer-1 aggregate: 2 edges/wave (32-lane halves), 8 feat/lane, w1 precomputed --
__global__ __launch_bounds__(256) void agg1_kernel(
    const unsigned short* __restrict__ h1b, const float* __restrict__ w1,
    const int* __restrict__ srcs, const int* __restrict__ offsets,
    const float* __restrict__ bias, unsigned short* __restrict__ hactb) {
  const int wv = threadIdx.x >> 6;
  const int lane = threadIdx.x & 63;
  const int n = blockIdx.x * 4 + wv;
  if (n >= N_NODESC) return;
  const int half = lane >> 5;
  const int l = lane & 31;
  const int h = l >> 3;
  const int beg = offsets[n], end = offsets[n + 1];

  float wsum = 0.f;
  float acc[8] = {0.f, 0.f, 0.f, 0.f, 0.f, 0.f, 0.f, 0.f};
  int i = beg;
  for (; i + 4 <= end; i += 4) {
    const int eA = i + half, eB = i + 2 + half;
    const int sA = srcs[eA];
    const int sB = srcs[eB];
    const float aA = w1[((unsigned)eA << 2) + h];
    const float aB = w1[((unsigned)eB << 2) + h];
    const uint4 hA = *reinterpret_cast<const uint4*>(h1b + ((unsigned)sA << 8) + l * 8);
    const uint4 hB = *reinterpret_cast<const uint4*>(h1b + ((unsigned)sB << 8) + l * 8);
    wsum += aA + aB;
    acc[0] += aA * blo(hA.x) + aB * blo(hB.x);
    acc[1] += aA * bhi(hA.x) + aB * bhi(hB.x);
    acc[2] += aA * blo(hA.y) + aB * blo(hB.y);
    acc[3] += aA * bhi(hA.y) + aB * bhi(hB.y);
    acc[4] += aA * blo(hA.z) + aB * blo(hB.z);
    acc[5] += aA * bhi(hA.z) + aB * bhi(hB.z);
    acc[6] += aA * blo(hA.w) + aB * blo(hB.w);
    acc[7] += aA * bhi(hA.w) + aB * bhi(hB.w);
  }
  for (; i < end; i += 2) {
    const int e = i + half;
    if (e < end) {
      const int s = srcs[e];
      const float a = w1[((unsigned)e << 2) + h];
      const uint4 hv = *reinterpret_cast<const uint4*>(h1b + ((unsigned)s << 8) + l * 8);
      wsum += a;
      acc[0] += a * blo(hv.x); acc[1] += a * bhi(hv.x);
      acc[2] += a * blo(hv.y); acc[3] += a * bhi(hv.y);
      acc[4] += a * blo(hv.z); acc[5] += a * bhi(hv.z);
      acc[6] += a * blo(hv.w); acc[7] += a * bhi(hv.w);
    }
  }
#pragma unroll
  for (int k = 0; k < 8; ++k) acc[k] += __shfl_xor(acc[k], 32);
  wsum += __shfl_xor(wsum, 32);
  if (half == 0) {
    const float inv = 1.f / (wsum + 1e-16f);
    const int f = l * 8;
    const float4 b0 = *reinterpret_cast<const float4*>(bias + f);
    const float4 b1 = *reinterpret_cast<const float4*>(bias + f + 4);
    float v0 = acc[0] * inv + b0.x; v0 = v0 > 0.f ? v0 : __expf(v0) - 1.f;
    float v1 = acc[1] * inv + b0.y; v1 = v1 > 0.f ? v1 : __expf(v1) - 1.f;
    float v2 = acc[2] * inv + b0.z; v2 = v2 > 0.f ? v2 : __expf(v2) - 1.f;
    float v3 = acc[3] * inv + b0.w; v3 = v3 > 0.f ? v3 : __expf(v3) - 1.f;
    float v4 = acc[4] * inv + b1.x; v4 = v4 > 0.f ? v4 : __expf(v4) - 1.f;
    float v5 = acc[5] * inv + b1.y; v5 = v5 > 0.f ? v5 : __expf(v5) - 1.f;
    float v6 = acc[6] * inv + b1.z; v6 = v6 > 0.f ? v6 : __expf(v6) - 1.f;
    float v7 = acc[7] * inv + b1.w; v7 = v7 > 0.f ? v7 : __expf(v7) - 1.f;
    uint4 st;
    st.x = (unsigned)f2bf(v0) | ((unsigned)f2bf(v1) << 16);
    st.y = (unsigned)f2bf(v2) | ((unsigned)f2bf(v3) << 16);
    st.z = (unsigned)f2bf(v4) | ((unsigned)f2bf(v5) << 16);
    st.w = (unsigned)f2bf(v6) | ((unsigned)f2bf(v7) << 16);
    *reinterpret_cast<uint4*>(hactb + ((unsigned)n << 8) + f) = st;
  }
}

// ---------- layer-2 softmax-aggregate: 2 edges/wave, 2 classes/lane (l<20) --------------
__global__ __launch_bounds__(256) void agg2_kernel(
    const unsigned short* __restrict__ g2b, const float* __restrict__ esrc,
    const float* __restrict__ edst, const int* __restrict__ srcs,
    const int* __restrict__ offsets, float* __restrict__ out) {
  const int wv = threadIdx.x >> 6;
  const int lane = threadIdx.x & 63;
  const int n = blockIdx.x * 4 + wv;
  if (n >= N_NODESC) return;
  const int half = lane >> 5;
  const int l = lane & 31;
  const bool act = l < (NCLASSC / 2);
  const int beg = offsets[n], end = offsets[n + 1];
  const float ed = edst[n];

  float wsum = 0.f, acc0 = 0.f, acc1 = 0.f;
  int i = beg;
  for (; i + 4 <= end; i += 4) {
    const int sA = srcs[i + half];
    const int sB = srcs[i + 2 + half];
    float tA = esrc[sA] + ed;
    float tB = esrc[sB] + ed;
    unsigned int gA = 0, gB = 0;
    if (act) {
      gA = *reinterpret_cast<const unsigned int*>(g2b + (unsigned)sA * NCLASSC + l * 2);
      gB = *reinterpret_cast<const unsigned int*>(g2b + (unsigned)sB * NCLASSC + l * 2);
    }
    tA = tA > 0.f ? tA : 0.2f * tA;
    tB = tB > 0.f ? tB : 0.2f * tB;
    const float aA = __expf(tA), aB = __expf(tB);
    wsum += aA + aB;
    acc0 += aA * blo(gA) + aB * blo(gB);
    acc1 += aA * bhi(gA) + aB * bhi(gB);
  }
  for (; i < end; i += 2) {
    const int e = i + half;
    if (e < end) {
      const int s = srcs[e];
      float t = esrc[s] + ed;
      unsigned int g = 0;
      if (act) g = *reinterpret_cast<const unsigned int*>(g2b + (unsigned)s * NCLASSC + l * 2);
      t = t > 0.f ? t : 0.2f * t;
      const float a = __expf(t);
      wsum += a;
      acc0 += a * blo(g);
      acc1 += a * bhi(g);
    }
  }
  acc0 += __shfl_xor(acc0, 32);
  acc1 += __shfl_xor(acc1, 32);
  wsum += __shfl_xor(wsum, 32);
  if (half == 0 && act) {
    const float inv = 1.f / (wsum + 1e-16f);
    float2 o;
    o.x = acc0 * inv;
    o.y = acc1 * inv;
    *reinterpret_cast<float2*>(out + (size_t)n * NCLASSC + l * 2) = o;
  }
}

extern "C" void kernel_launch(void* const* d_in, const int* in_sizes, int n_in,
                              void* d_out, int out_size, void* d_ws, size_t ws_size,
                              hipStream_t stream) {
  const float* x   = (const float*)d_in[0];
  const int*   ei  = (const int*)d_in[1];
  const float* W1  = (const float*)d_in[2];
  const float* b1  = (const float*)d_in[3];
  const float* B1  = (const float*)d_in[4];
  const float* cs1 = (const float*)d_in[5];
  const float* cd1 = (const float*)d_in[6];
  const float* W2  = (const float*)d_in[7];
  const float* B2  = (const float*)d_in[8];
  const float* cs2 = (const float*)d_in[9];
  const float* cd2 = (const float*)d_in[10];
  const int* srcA = ei;
  const int* dstA = ei + N_EDGESC;
  float* out = (float*)d_out;

  char* ws = (char*)d_ws;
  size_t off = 0;
  auto alloc = [&](size_t bytes) -> void* {
    void* p = ws + off;
    off += (bytes + 255) & ~(size_t)255;
    return p;
  };
  unsigned short* h1b   = (unsigned short*)alloc((size_t)N_NODESC * HD1C * 2);
  unsigned short* hactb = (unsigned short*)alloc((size_t)N_NODESC * HD1C * 2);
  unsigned short* g2b   = (unsigned short*)alloc((size_t)N_NODESC * NCLASSC * 2);
  unsigned short* W1T   = (unsigned short*)alloc((size_t)W1TROWS * NFEATC * 2);
  unsigned short* W2T   = (unsigned short*)alloc((size_t)W2TROWS * HD1C * 2);
  float* esrc1  = (float*)alloc((size_t)N_NODESC * NHEADC * 4);
  float* edst1  = (float*)alloc((size_t)N_NODESC * NHEADC * 4);
  float* esrc2  = (float*)alloc((size_t)N_NODESC * 4);
  float* edst2  = (float*)alloc((size_t)N_NODESC * 4);
  float* w1     = (float*)alloc((size_t)N_EDGESC * NHEADC * 4);
  int* counts   = (int*)alloc((size_t)N_NODESC * 4);
  int* offsets  = (int*)alloc((size_t)(N_NODESC + 1) * 4);
  int* srcs_csr = (int*)alloc((size_t)N_EDGESC * 4);

  hipMemsetAsync(counts, 0, (size_t)N_NODESC * 4, stream);

  // prep (W1T, W2T, dst histogram)
  prep_kernel<<<PREP_NB, 256, 0, stream>>>(W1, B1, W1T, W2, B2, W2T, dstA, counts);

  // layer-1 GEMM (+ attn scalars) -- needs only W1T
  gemm1_fused<<<(N_NODESC + 255) / 256, 256, 0, stream>>>(x, W1T, cs1, cd1, h1b, esrc1,
                                                          edst1);

  // CSR offsets + scatter fused with layer-1 edge weights
  scan50k<<<1, 1024, 0, stream>>>(counts, offsets);
  scatter_w1<<<(N_EDGESC + 255) / 256, 256, 0, stream>>>(dstA, srcA, offsets, counts,
                                                         esrc1, edst1, srcs_csr, w1);

  agg1_kernel<<<(N_NODESC + 3) / 4, 256, 0, stream>>>(h1b, w1, srcs_csr, offsets, b1,
                                                      hactb);

  // layer 2
  gemm2_fused<<<(N_NODESC + 255) / 256, 256, 0, stream>>>(hactb, W2T, cs2, cd2, g2b, esrc2,
                                                          edst2);
  agg2_kernel<<<(N_NODESC + 3) / 4, 256, 0, stream>>>(g2b, esrc2, edst2, srcs_csr, offsets,
                                                      out);
}

// Round 9
// 295.393 us; speedup vs baseline: 1.2624x; 1.2624x over previous
//
#include <hip/hip_runtime.h>

#define N_NODESC 50000
#define N_EDGESC 800000
#define NFEATC 128
#define NHIDC 64
#define NHEADC 4
#define NBASEC 8
#define NCLASSC 40
#define HD1C (NHEADC * NHIDC)        // 256
#define W1TROWS 320                  // 256 + 8, padded to 64-multiple
#define W2TROWS 64                   // 40 + 8, padded

typedef __attribute__((ext_vector_type(8))) short bf16x8;
typedef __attribute__((ext_vector_type(4))) float f32x4;

__device__ inline float bf2f(unsigned short u) {
  union { unsigned int i; float f; } v;
  v.i = ((unsigned int)u) << 16;
  return v.f;
}
__device__ inline float blo(unsigned int u) {
  union { unsigned int i; float f; } v; v.i = u << 16; return v.f;
}
__device__ inline float bhi(unsigned int u) {
  union { unsigned int i; float f; } v; v.i = u & 0xffff0000u; return v.f;
}
__device__ inline unsigned short f2bf(float x) {
  union { float f; unsigned int i; } v;
  v.f = x;
  unsigned int r = v.i + 0x7FFF + ((v.i >> 16) & 1);  // RNE
  return (unsigned short)(r >> 16);
}

// ======== layer-1 fused: [h1 | s1] = x @ [W1|B1] (MFMA, x staged in LDS once),
//          esrc1/edst1 computed in-epilogue from the s-columns ========
__global__ __launch_bounds__(256) void gemm1_fused(
    const float* __restrict__ x, const unsigned short* __restrict__ W1T,
    const float* __restrict__ cs1, const float* __restrict__ cd1,
    unsigned short* __restrict__ h1b, float* __restrict__ esrc, float* __restrict__ edst) {
  __shared__ unsigned short As[256 * 132];
  __shared__ float sS[256 * 8];
  const int tid = threadIdx.x;
  const int wave = tid >> 6, lane = tid & 63;
  const int row0 = blockIdx.x * 256;

#pragma unroll
  for (int p = 0; p < 32; ++p) {
    const int g4 = p * 256 + tid;
    const int r = g4 >> 5;
    const int k4 = g4 & 31;
    int grow = row0 + r;
    grow = grow < N_NODESC ? grow : N_NODESC - 1;
    const float4 v = *reinterpret_cast<const float4*>(x + (size_t)grow * NFEATC + k4 * 4);
    ushort4 o;
    o.x = f2bf(v.x); o.y = f2bf(v.y); o.z = f2bf(v.z); o.w = f2bf(v.w);
    *reinterpret_cast<ushort4*>(&As[r * 132 + k4 * 4]) = o;
  }
  __syncthreads();

  const int lm = lane & 15, q = lane >> 4, kq = q * 8;
  for (int t = 0; t < 5; ++t) {
    const int n0 = t * 64;
    f32x4 acc[4][4] = {};
#pragma unroll
    for (int k0 = 0; k0 < NFEATC; k0 += 32) {
      bf16x8 af[4], bfr[4];
#pragma unroll
      for (int mi = 0; mi < 4; ++mi)
        af[mi] = *reinterpret_cast<const bf16x8*>(&As[(wave * 64 + mi * 16 + lm) * 132 + k0 + kq]);
#pragma unroll
      for (int ni = 0; ni < 4; ++ni)
        bfr[ni] = *reinterpret_cast<const bf16x8*>(W1T + (size_t)(n0 + ni * 16 + lm) * NFEATC + k0 + kq);
#pragma unroll
      for (int mi = 0; mi < 4; ++mi)
#pragma unroll
        for (int ni = 0; ni < 4; ++ni)
          acc[mi][ni] = __builtin_amdgcn_mfma_f32_16x16x32_bf16(af[mi], bfr[ni], acc[mi][ni],
                                                                0, 0, 0);
    }
    if (t < 4) {
#pragma unroll
      for (int mi = 0; mi < 4; ++mi)
#pragma unroll
        for (int r = 0; r < 4; ++r) {
          const int row = row0 + wave * 64 + mi * 16 + q * 4 + r;
          if (row >= N_NODESC) continue;
#pragma unroll
          for (int ni = 0; ni < 4; ++ni)
            h1b[(size_t)row * HD1C + n0 + ni * 16 + lm] = f2bf(acc[mi][ni][r]);
        }
    } else {
      if (lm < 8) {
#pragma unroll
        for (int mi = 0; mi < 4; ++mi)
#pragma unroll
          for (int r = 0; r < 4; ++r)
            sS[(wave * 64 + mi * 16 + q * 4 + r) * 8 + lm] = acc[mi][0][r];
      }
      const int rloc = wave * 64 + lane;
      const int grow = row0 + rloc;
      if (grow < N_NODESC) {
        float sb[8];
#pragma unroll
        for (int b = 0; b < 8; ++b) sb[b] = sS[rloc * 8 + b];
#pragma unroll
        for (int h = 0; h < NHEADC; ++h) {
          float a = 0.f, d = 0.f;
#pragma unroll
          for (int b = 0; b < NBASEC; ++b) {
            a += sb[b] * cs1[b * NHEADC + h];
            d += sb[b] * cd1[b * NHEADC + h];
          }
          esrc[grow * NHEADC + h] = a;
          edst[grow * NHEADC + h] = d;
        }
      }
    }
  }
}

// ======== layer-2 fused: [g2 | s2] = hact @ [W2|B2], esrc2/edst2 in-epilogue ========
__global__ __launch_bounds__(256) void gemm2_fused(
    const unsigned short* __restrict__ A, const unsigned short* __restrict__ W2T,
    const float* __restrict__ cs2, const float* __restrict__ cd2,
    unsigned short* __restrict__ g2b, float* __restrict__ esrc, float* __restrict__ edst) {
  __shared__ float sS[256 * 8];
  const int wave = threadIdx.x >> 6;
  const int lane = threadIdx.x & 63;
  const int m0 = blockIdx.x * 256 + wave * 64;
  const int lm = lane & 15, q = lane >> 4, kq = q * 8;
  f32x4 acc[4][4] = {};

  for (int k0 = 0; k0 < HD1C; k0 += 32) {
    bf16x8 af[4], bfr[4];
#pragma unroll
    for (int mi = 0; mi < 4; ++mi) {
      int row = m0 + mi * 16 + lm;
      row = row < N_NODESC ? row : N_NODESC - 1;
      af[mi] = *reinterpret_cast<const bf16x8*>(A + (size_t)row * HD1C + k0 + kq);
    }
#pragma unroll
    for (int ni = 0; ni < 4; ++ni)
      bfr[ni] = *reinterpret_cast<const bf16x8*>(W2T + (size_t)(ni * 16 + lm) * HD1C + k0 + kq);
#pragma unroll
    for (int mi = 0; mi < 4; ++mi)
#pragma unroll
      for (int ni = 0; ni < 4; ++ni)
        acc[mi][ni] = __builtin_amdgcn_mfma_f32_16x16x32_bf16(af[mi], bfr[ni], acc[mi][ni],
                                                              0, 0, 0);
  }
#pragma unroll
  for (int mi = 0; mi < 4; ++mi)
#pragma unroll
    for (int r = 0; r < 4; ++r) {
      const int row = m0 + mi * 16 + q * 4 + r;
      if (row >= N_NODESC) continue;
#pragma unroll
      for (int ni = 0; ni < 3; ++ni) {
        const int col = ni * 16 + lm;
        if (col < NCLASSC) g2b[(size_t)row * NCLASSC + col] = f2bf(acc[mi][ni][r]);
      }
    }
  if (lm >= 8) {
#pragma unroll
    for (int mi = 0; mi < 4; ++mi)
#pragma unroll
      for (int r = 0; r < 4; ++r)
        sS[(wave * 64 + mi * 16 + q * 4 + r) * 8 + (lm - 8)] = acc[mi][2][r];
  }
  const int rloc = wave * 64 + lane;
  const int grow = blockIdx.x * 256 + rloc;
  if (grow < N_NODESC) {
    float sb[8];
#pragma unroll
    for (int b = 0; b < 8; ++b) sb[b] = sS[rloc * 8 + b];
    float a = 0.f, d = 0.f;
#pragma unroll
    for (int b = 0; b < NBASEC; ++b) {
      a += sb[b] * cs2[b];
      d += sb[b] * cd2[b];
    }
    esrc[grow] = a;
    edst[grow] = d;
  }
}

// ---------------- fused prep: W1T | W2T | dst histogram ----------------
#define W1T_NB ((W1TROWS * NFEATC + 255) / 256)                 // 160
#define W2T_NB ((W2TROWS * HD1C + 255) / 256)                   // 64
#define HIST_NB ((N_EDGESC + 255) / 256)                        // 3125
#define PREP_NB (W1T_NB + W2T_NB + HIST_NB)

__global__ __launch_bounds__(256) void prep_kernel(
    const float* __restrict__ W1, const float* __restrict__ B1,
    unsigned short* __restrict__ W1T,
    const float* __restrict__ W2, const float* __restrict__ B2,
    unsigned short* __restrict__ W2T,
    const int* __restrict__ dst, int* __restrict__ counts) {
  int b = blockIdx.x;
  if (b < W1T_NB) {
    const int i = b * 256 + threadIdx.x;
    if (i < W1TROWS * NFEATC) {
      const int n = i / NFEATC, k = i - n * NFEATC;
      float v = 0.f;
      if (n < HD1C) v = W1[(size_t)k * HD1C + n];
      else if (n < HD1C + NBASEC) v = B1[(size_t)k * NBASEC + (n - HD1C)];
      W1T[i] = f2bf(v);
    }
    return;
  }
  b -= W1T_NB;
  if (b < W2T_NB) {
    const int i = b * 256 + threadIdx.x;
    if (i < W2TROWS * HD1C) {
      const int n = i / HD1C, k = i - n * HD1C;
      float v = 0.f;
      if (n < NCLASSC) v = W2[(size_t)k * NCLASSC + n];
      else if (n < NCLASSC + NBASEC) v = B2[(size_t)k * NBASEC + (n - NCLASSC)];
      W2T[i] = f2bf(v);
    }
    return;
  }
  b -= W2T_NB;
  {
    const int e = b * 256 + threadIdx.x;
    if (e < N_EDGESC) atomicAdd(&counts[dst[e]], 1);
  }
}

// ---------------- 3-phase parallel scan ----------------
#define SCAN_NB ((N_NODESC + 255) / 256)   // 196

__global__ void reduce_counts(const int* __restrict__ counts, int* __restrict__ bsums) {
  __shared__ int sm[256];
  const int i = blockIdx.x * 256 + threadIdx.x;
  sm[threadIdx.x] = (i < N_NODESC) ? counts[i] : 0;
  __syncthreads();
  for (int d = 128; d > 0; d >>= 1) {
    if (threadIdx.x < (unsigned)d) sm[threadIdx.x] += sm[threadIdx.x + d];
    __syncthreads();
  }
  if (threadIdx.x == 0) bsums[blockIdx.x] = sm[0];
}

__global__ void scan_bsums_k(int* __restrict__ bsums) {
  __shared__ int sm[256];
  const int v = (threadIdx.x < SCAN_NB) ? bsums[threadIdx.x] : 0;
  sm[threadIdx.x] = v;
  __syncthreads();
  for (int d = 1; d < 256; d <<= 1) {
    const int t = (threadIdx.x >= (unsigned)d) ? sm[threadIdx.x - d] : 0;
    __syncthreads();
    sm[threadIdx.x] += t;
    __syncthreads();
  }
  if (threadIdx.x < SCAN_NB) bsums[threadIdx.x] = sm[threadIdx.x] - v;  // exclusive
}

__global__ void scan_final(const int* __restrict__ counts, const int* __restrict__ bsums,
                           int* __restrict__ offsets) {
  __shared__ int sm[256];
  const int i = blockIdx.x * 256 + threadIdx.x;
  const int v = (i < N_NODESC) ? counts[i] : 0;
  sm[threadIdx.x] = v;
  __syncthreads();
  for (int d = 1; d < 256; d <<= 1) {
    const int t = (threadIdx.x >= (unsigned)d) ? sm[threadIdx.x - d] : 0;
    __syncthreads();
    sm[threadIdx.x] += t;
    __syncthreads();
  }
  if (i < N_NODESC) offsets[i] = bsums[blockIdx.x] + sm[threadIdx.x] - v;
  if (i == 0) offsets[N_NODESC] = N_EDGESC;
}

// -------- scatter + layer-1 edge-weight precompute: srcs_csr, w1[pos][h]=exp(leaky(e)) ----
__global__ void scatter_w1(const int* __restrict__ dst, const int* __restrict__ src,
                           const int* __restrict__ offsets, int* __restrict__ counts,
                           const float* __restrict__ esrc, const float* __restrict__ edst,
                           int* __restrict__ srcs_csr, float* __restrict__ w1) {
  const int e = blockIdx.x * blockDim.x + threadIdx.x;
  if (e >= N_EDGESC) return;
  const int n = dst[e];
  const int s = src[e];
  const int pos = offsets[n] + atomicSub(&counts[n], 1) - 1;
  srcs_csr[pos] = s;
  const float4 es = *reinterpret_cast<const float4*>(esrc + (size_t)s * NHEADC);
  const float4 ed = *reinterpret_cast<const float4*>(edst + (size_t)n * NHEADC);
  float4 w;
  float t;
  t = es.x + ed.x; t = t > 0.f ? t : 0.2f * t; w.x = __expf(t);
  t = es.y + ed.y; t = t > 0.f ? t : 0.2f * t; w.y = __expf(t);
  t = es.z + ed.z; t = t > 0.f ? t : 0.2f * t; w.z = __expf(t);
  t = es.w + ed.w; t = t > 0.f ? t : 0.2f * t; w.w = __expf(t);
  *reinterpret_cast<float4*>(w1 + (size_t)pos * NHEADC) = w;
}

// ---------- layer-1 aggregate: 2 edges/wave (32-lane halves), 8 feat/lane, w1 precomputed --
__global__ __launch_bounds__(256) void agg1_kernel(
    const unsigned short* __restrict__ h1b, const float* __restrict__ w1,
    const int* __restrict__ srcs, const int* __restrict__ offsets,
    const float* __restrict__ bias, unsigned short* __restrict__ hactb) {
  const int wv = threadIdx.x >> 6;
  const int lane = threadIdx.x & 63;
  const int n = blockIdx.x * 4 + wv;
  if (n >= N_NODESC) return;
  const int half = lane >> 5;
  const int l = lane & 31;
  const int h = l >> 3;
  const int beg = offsets[n], end = offsets[n + 1];

  float wsum = 0.f;
  float acc[8] = {0.f, 0.f, 0.f, 0.f, 0.f, 0.f, 0.f, 0.f};
  int i = beg;
  for (; i + 4 <= end; i += 4) {
    const int eA = i + half, eB = i + 2 + half;
    const int sA = srcs[eA];
    const int sB = srcs[eB];
    const float aA = w1[((unsigned)eA << 2) + h];
    const float aB = w1[((unsigned)eB << 2) + h];
    const uint4 hA = *reinterpret_cast<const uint4*>(h1b + ((unsigned)sA << 8) + l * 8);
    const uint4 hB = *reinterpret_cast<const uint4*>(h1b + ((unsigned)sB << 8) + l * 8);
    wsum += aA + aB;
    acc[0] += aA * blo(hA.x) + aB * blo(hB.x);
    acc[1] += aA * bhi(hA.x) + aB * bhi(hB.x);
    acc[2] += aA * blo(hA.y) + aB * blo(hB.y);
    acc[3] += aA * bhi(hA.y) + aB * bhi(hB.y);
    acc[4] += aA * blo(hA.z) + aB * blo(hB.z);
    acc[5] += aA * bhi(hA.z) + aB * bhi(hB.z);
    acc[6] += aA * blo(hA.w) + aB * blo(hB.w);
    acc[7] += aA * bhi(hA.w) + aB * bhi(hB.w);
  }
  for (; i < end; i += 2) {
    const int e = i + half;
    if (e < end) {
      const int s = srcs[e];
      const float a = w1[((unsigned)e << 2) + h];
      const uint4 hv = *reinterpret_cast<const uint4*>(h1b + ((unsigned)s << 8) + l * 8);
      wsum += a;
      acc[0] += a * blo(hv.x); acc[1] += a * bhi(hv.x);
      acc[2] += a * blo(hv.y); acc[3] += a * bhi(hv.y);
      acc[4] += a * blo(hv.z); acc[5] += a * bhi(hv.z);
      acc[6] += a * blo(hv.w); acc[7] += a * bhi(hv.w);
    }
  }
#pragma unroll
  for (int k = 0; k < 8; ++k) acc[k] += __shfl_xor(acc[k], 32);
  wsum += __shfl_xor(wsum, 32);
  if (half == 0) {
    const float inv = 1.f / (wsum + 1e-16f);
    const int f = l * 8;
    const float4 b0 = *reinterpret_cast<const float4*>(bias + f);
    const float4 b1 = *reinterpret_cast<const float4*>(bias + f + 4);
    float v0 = acc[0] * inv + b0.x; v0 = v0 > 0.f ? v0 : __expf(v0) - 1.f;
    float v1 = acc[1] * inv + b0.y; v1 = v1 > 0.f ? v1 : __expf(v1) - 1.f;
    float v2 = acc[2] * inv + b0.z; v2 = v2 > 0.f ? v2 : __expf(v2) - 1.f;
    float v3 = acc[3] * inv + b0.w; v3 = v3 > 0.f ? v3 : __expf(v3) - 1.f;
    float v4 = acc[4] * inv + b1.x; v4 = v4 > 0.f ? v4 : __expf(v4) - 1.f;
    float v5 = acc[5] * inv + b1.y; v5 = v5 > 0.f ? v5 : __expf(v5) - 1.f;
    float v6 = acc[6] * inv + b1.z; v6 = v6 > 0.f ? v6 : __expf(v6) - 1.f;
    float v7 = acc[7] * inv + b1.w; v7 = v7 > 0.f ? v7 : __expf(v7) - 1.f;
    uint4 st;
    st.x = (unsigned)f2bf(v0) | ((unsigned)f2bf(v1) << 16);
    st.y = (unsigned)f2bf(v2) | ((unsigned)f2bf(v3) << 16);
    st.z = (unsigned)f2bf(v4) | ((unsigned)f2bf(v5) << 16);
    st.w = (unsigned)f2bf(v6) | ((unsigned)f2bf(v7) << 16);
    *reinterpret_cast<uint4*>(hactb + ((unsigned)n << 8) + f) = st;
  }
}

// ---------- layer-2 softmax-aggregate: 2 edges/wave, 2 classes/lane (l<20) --------------
__global__ __launch_bounds__(256) void agg2_kernel(
    const unsigned short* __restrict__ g2b, const float* __restrict__ esrc,
    const float* __restrict__ edst, const int* __restrict__ srcs,
    const int* __restrict__ offsets, float* __restrict__ out) {
  const int wv = threadIdx.x >> 6;
  const int lane = threadIdx.x & 63;
  const int n = blockIdx.x * 4 + wv;
  if (n >= N_NODESC) return;
  const int half = lane >> 5;
  const int l = lane & 31;
  const bool act = l < (NCLASSC / 2);
  const int beg = offsets[n], end = offsets[n + 1];
  const float ed = edst[n];

  float wsum = 0.f, acc0 = 0.f, acc1 = 0.f;
  int i = beg;
  for (; i + 4 <= end; i += 4) {
    const int sA = srcs[i + half];
    const int sB = srcs[i + 2 + half];
    float tA = esrc[sA] + ed;
    float tB = esrc[sB] + ed;
    unsigned int gA = 0, gB = 0;
    if (act) {
      gA = *reinterpret_cast<const unsigned int*>(g2b + (unsigned)sA * NCLASSC + l * 2);
      gB = *reinterpret_cast<const unsigned int*>(g2b + (unsigned)sB * NCLASSC + l * 2);
    }
    tA = tA > 0.f ? tA : 0.2f * tA;
    tB = tB > 0.f ? tB : 0.2f * tB;
    const float aA = __expf(tA), aB = __expf(tB);
    wsum += aA + aB;
    acc0 += aA * blo(gA) + aB * blo(gB);
    acc1 += aA * bhi(gA) + aB * bhi(gB);
  }
  for (; i < end; i += 2) {
    const int e = i + half;
    if (e < end) {
      const int s = srcs[e];
      float t = esrc[s] + ed;
      unsigned int g = 0;
      if (act) g = *reinterpret_cast<const unsigned int*>(g2b + (unsigned)s * NCLASSC + l * 2);
      t = t > 0.f ? t : 0.2f * t;
      const float a = __expf(t);
      wsum += a;
      acc0 += a * blo(g);
      acc1 += a * bhi(g);
    }
  }
  acc0 += __shfl_xor(acc0, 32);
  acc1 += __shfl_xor(acc1, 32);
  wsum += __shfl_xor(wsum, 32);
  if (half == 0 && act) {
    const float inv = 1.f / (wsum + 1e-16f);
    float2 o;
    o.x = acc0 * inv;
    o.y = acc1 * inv;
    *reinterpret_cast<float2*>(out + (size_t)n * NCLASSC + l * 2) = o;
  }
}

extern "C" void kernel_launch(void* const* d_in, const int* in_sizes, int n_in,
                              void* d_out, int out_size, void* d_ws, size_t ws_size,
                              hipStream_t stream) {
  const float* x   = (const float*)d_in[0];
  const int*   ei  = (const int*)d_in[1];
  const float* W1  = (const float*)d_in[2];
  const float* b1  = (const float*)d_in[3];
  const float* B1  = (const float*)d_in[4];
  const float* cs1 = (const float*)d_in[5];
  const float* cd1 = (const float*)d_in[6];
  const float* W2  = (const float*)d_in[7];
  const float* B2  = (const float*)d_in[8];
  const float* cs2 = (const float*)d_in[9];
  const float* cd2 = (const float*)d_in[10];
  const int* srcA = ei;
  const int* dstA = ei + N_EDGESC;
  float* out = (float*)d_out;

  char* ws = (char*)d_ws;
  size_t off = 0;
  auto alloc = [&](size_t bytes) -> void* {
    void* p = ws + off;
    off += (bytes + 255) & ~(size_t)255;
    return p;
  };
  unsigned short* h1b   = (unsigned short*)alloc((size_t)N_NODESC * HD1C * 2);
  unsigned short* hactb = (unsigned short*)alloc((size_t)N_NODESC * HD1C * 2);
  unsigned short* g2b   = (unsigned short*)alloc((size_t)N_NODESC * NCLASSC * 2);
  unsigned short* W1T   = (unsigned short*)alloc((size_t)W1TROWS * NFEATC * 2);
  unsigned short* W2T   = (unsigned short*)alloc((size_t)W2TROWS * HD1C * 2);
  float* esrc1  = (float*)alloc((size_t)N_NODESC * NHEADC * 4);
  float* edst1  = (float*)alloc((size_t)N_NODESC * NHEADC * 4);
  float* esrc2  = (float*)alloc((size_t)N_NODESC * 4);
  float* edst2  = (float*)alloc((size_t)N_NODESC * 4);
  float* w1     = (float*)alloc((size_t)N_EDGESC * NHEADC * 4);
  int* counts   = (int*)alloc((size_t)N_NODESC * 4);
  int* offsets  = (int*)alloc((size_t)(N_NODESC + 1) * 4);
  int* bsums    = (int*)alloc((size_t)SCAN_NB * 4);
  int* srcs_csr = (int*)alloc((size_t)N_EDGESC * 4);

  hipMemsetAsync(counts, 0, (size_t)N_NODESC * 4, stream);

  // prep (W1T, W2T, dst histogram)
  prep_kernel<<<PREP_NB, 256, 0, stream>>>(W1, B1, W1T, W2, B2, W2T, dstA, counts);

  // layer-1 GEMM (+ attn scalars) -- needs only W1T
  gemm1_fused<<<(N_NODESC + 255) / 256, 256, 0, stream>>>(x, W1T, cs1, cd1, h1b, esrc1,
                                                          edst1);

  // CSR offsets (3-phase parallel scan) + scatter fused with layer-1 edge weights
  reduce_counts<<<SCAN_NB, 256, 0, stream>>>(counts, bsums);
  scan_bsums_k<<<1, 256, 0, stream>>>(bsums);
  scan_final<<<SCAN_NB, 256, 0, stream>>>(counts, bsums, offsets);
  scatter_w1<<<(N_EDGESC + 255) / 256, 256, 0, stream>>>(dstA, srcA, offsets, counts,
                                                         esrc1, edst1, srcs_csr, w1);

  agg1_kernel<<<(N_NODESC + 3) / 4, 256, 0, stream>>>(h1b, w1, srcs_csr, offsets, b1,
                                                      hactb);

  // layer 2
  gemm2_fused<<<(N_NODESC + 255) / 256, 256, 0, stream>>>(hactb, W2T, cs2, cd2, g2b, esrc2,
                                                          edst2);
  agg2_kernel<<<(N_NODESC + 3) / 4, 256, 0, stream>>>(g2b, esrc2, edst2, srcs_csr, offsets,
                                                      out);
}

// Round 10
// 285.932 us; speedup vs baseline: 1.3041x; 1.0331x over previous
//
#include <hip/hip_runtime.h>

#define N_NODESC 50000
#define N_EDGESC 800000
#define NFEATC 128
#define NHIDC 64
#define NHEADC 4
#define NBASEC 8
#define NCLASSC 40
#define HD1C (NHEADC * NHIDC)        // 256
#define W1TROWS 320                  // 256 + 8, padded to 64-multiple
#define W2TROWS 64                   // 40 + 8, padded

typedef __attribute__((ext_vector_type(8))) short bf16x8;
typedef __attribute__((ext_vector_type(4))) float f32x4;

__device__ inline float bf2f(unsigned short u) {
  union { unsigned int i; float f; } v;
  v.i = ((unsigned int)u) << 16;
  return v.f;
}
__device__ inline float blo(unsigned int u) {
  union { unsigned int i; float f; } v; v.i = u << 16; return v.f;
}
__device__ inline float bhi(unsigned int u) {
  union { unsigned int i; float f; } v; v.i = u & 0xffff0000u; return v.f;
}
__device__ inline unsigned short f2bf(float x) {
  union { float f; unsigned int i; } v;
  v.f = x;
  unsigned int r = v.i + 0x7FFF + ((v.i >> 16) & 1);  // RNE
  return (unsigned short)(r >> 16);
}

// ======== layer-1 fused: [h1 | s1] = x @ [W1|B1] (MFMA, x staged in LDS once),
//          esrc1/edst1 computed in-epilogue from the s-columns ========
__global__ __launch_bounds__(256) void gemm1_fused(
    const float* __restrict__ x, const unsigned short* __restrict__ W1T,
    const float* __restrict__ cs1, const float* __restrict__ cd1,
    unsigned short* __restrict__ h1b, float* __restrict__ esrc, float* __restrict__ edst) {
  __shared__ unsigned short As[256 * 132];
  __shared__ float sS[256 * 8];
  const int tid = threadIdx.x;
  const int wave = tid >> 6, lane = tid & 63;
  const int row0 = blockIdx.x * 256;

#pragma unroll
  for (int p = 0; p < 32; ++p) {
    const int g4 = p * 256 + tid;
    const int r = g4 >> 5;
    const int k4 = g4 & 31;
    int grow = row0 + r;
    grow = grow < N_NODESC ? grow : N_NODESC - 1;
    const float4 v = *reinterpret_cast<const float4*>(x + (size_t)grow * NFEATC + k4 * 4);
    ushort4 o;
    o.x = f2bf(v.x); o.y = f2bf(v.y); o.z = f2bf(v.z); o.w = f2bf(v.w);
    *reinterpret_cast<ushort4*>(&As[r * 132 + k4 * 4]) = o;
  }
  __syncthreads();

  const int lm = lane & 15, q = lane >> 4, kq = q * 8;
  for (int t = 0; t < 5; ++t) {
    const int n0 = t * 64;
    f32x4 acc[4][4] = {};
#pragma unroll
    for (int k0 = 0; k0 < NFEATC; k0 += 32) {
      bf16x8 af[4], bfr[4];
#pragma unroll
      for (int mi = 0; mi < 4; ++mi)
        af[mi] = *reinterpret_cast<const bf16x8*>(&As[(wave * 64 + mi * 16 + lm) * 132 + k0 + kq]);
#pragma unroll
      for (int ni = 0; ni < 4; ++ni)
        bfr[ni] = *reinterpret_cast<const bf16x8*>(W1T + (size_t)(n0 + ni * 16 + lm) * NFEATC + k0 + kq);
#pragma unroll
      for (int mi = 0; mi < 4; ++mi)
#pragma unroll
        for (int ni = 0; ni < 4; ++ni)
          acc[mi][ni] = __builtin_amdgcn_mfma_f32_16x16x32_bf16(af[mi], bfr[ni], acc[mi][ni],
                                                                0, 0, 0);
    }
    if (t < 4) {
#pragma unroll
      for (int mi = 0; mi < 4; ++mi)
#pragma unroll
        for (int r = 0; r < 4; ++r) {
          const int row = row0 + wave * 64 + mi * 16 + q * 4 + r;
          if (row >= N_NODESC) continue;
#pragma unroll
          for (int ni = 0; ni < 4; ++ni)
            h1b[(size_t)row * HD1C + n0 + ni * 16 + lm] = f2bf(acc[mi][ni][r]);
        }
    } else {
      if (lm < 8) {
#pragma unroll
        for (int mi = 0; mi < 4; ++mi)
#pragma unroll
          for (int r = 0; r < 4; ++r)
            sS[(wave * 64 + mi * 16 + q * 4 + r) * 8 + lm] = acc[mi][0][r];
      }
      const int rloc = wave * 64 + lane;
      const int grow = row0 + rloc;
      if (grow < N_NODESC) {
        float sb[8];
#pragma unroll
        for (int b = 0; b < 8; ++b) sb[b] = sS[rloc * 8 + b];
#pragma unroll
        for (int h = 0; h < NHEADC; ++h) {
          float a = 0.f, d = 0.f;
#pragma unroll
          for (int b = 0; b < NBASEC; ++b) {
            a += sb[b] * cs1[b * NHEADC + h];
            d += sb[b] * cd1[b * NHEADC + h];
          }
          esrc[grow * NHEADC + h] = a;
          edst[grow * NHEADC + h] = d;
        }
      }
    }
  }
}

// ======== layer-2 fused: [g2 | s2] = hact @ [W2|B2], esrc2/edst2 in-epilogue ========
__global__ __launch_bounds__(256) void gemm2_fused(
    const unsigned short* __restrict__ A, const unsigned short* __restrict__ W2T,
    const float* __restrict__ cs2, const float* __restrict__ cd2,
    unsigned short* __restrict__ g2b, float* __restrict__ esrc, float* __restrict__ edst) {
  __shared__ float sS[256 * 8];
  const int wave = threadIdx.x >> 6;
  const int lane = threadIdx.x & 63;
  const int m0 = blockIdx.x * 256 + wave * 64;
  const int lm = lane & 15, q = lane >> 4, kq = q * 8;
  f32x4 acc[4][4] = {};

  for (int k0 = 0; k0 < HD1C; k0 += 32) {
    bf16x8 af[4], bfr[4];
#pragma unroll
    for (int mi = 0; mi < 4; ++mi) {
      int row = m0 + mi * 16 + lm;
      row = row < N_NODESC ? row : N_NODESC - 1;
      af[mi] = *reinterpret_cast<const bf16x8*>(A + (size_t)row * HD1C + k0 + kq);
    }
#pragma unroll
    for (int ni = 0; ni < 4; ++ni)
      bfr[ni] = *reinterpret_cast<const bf16x8*>(W2T + (size_t)(ni * 16 + lm) * HD1C + k0 + kq);
#pragma unroll
    for (int mi = 0; mi < 4; ++mi)
#pragma unroll
      for (int ni = 0; ni < 4; ++ni)
        acc[mi][ni] = __builtin_amdgcn_mfma_f32_16x16x32_bf16(af[mi], bfr[ni], acc[mi][ni],
                                                              0, 0, 0);
  }
#pragma unroll
  for (int mi = 0; mi < 4; ++mi)
#pragma unroll
    for (int r = 0; r < 4; ++r) {
      const int row = m0 + mi * 16 + q * 4 + r;
      if (row >= N_NODESC) continue;
#pragma unroll
      for (int ni = 0; ni < 3; ++ni) {
        const int col = ni * 16 + lm;
        if (col < NCLASSC) g2b[(size_t)row * NCLASSC + col] = f2bf(acc[mi][ni][r]);
      }
    }
  if (lm >= 8) {
#pragma unroll
    for (int mi = 0; mi < 4; ++mi)
#pragma unroll
      for (int r = 0; r < 4; ++r)
        sS[(wave * 64 + mi * 16 + q * 4 + r) * 8 + (lm - 8)] = acc[mi][2][r];
  }
  const int rloc = wave * 64 + lane;
  const int grow = blockIdx.x * 256 + rloc;
  if (grow < N_NODESC) {
    float sb[8];
#pragma unroll
    for (int b = 0; b < 8; ++b) sb[b] = sS[rloc * 8 + b];
    float a = 0.f, d = 0.f;
#pragma unroll
    for (int b = 0; b < NBASEC; ++b) {
      a += sb[b] * cs2[b];
      d += sb[b] * cd2[b];
    }
    esrc[grow] = a;
    edst[grow] = d;
  }
}

// ---------------- fused prep: W1T | W2T | dst histogram ----------------
#define W1T_NB ((W1TROWS * NFEATC + 255) / 256)                 // 160
#define W2T_NB ((W2TROWS * HD1C + 255) / 256)                   // 64
#define HIST_NB ((N_EDGESC + 255) / 256)                        // 3125
#define PREP_NB (W1T_NB + W2T_NB + HIST_NB)

__global__ __launch_bounds__(256) void prep_kernel(
    const float* __restrict__ W1, const float* __restrict__ B1,
    unsigned short* __restrict__ W1T,
    const float* __restrict__ W2, const float* __restrict__ B2,
    unsigned short* __restrict__ W2T,
    const int* __restrict__ dst, int* __restrict__ counts) {
  int b = blockIdx.x;
  if (b < W1T_NB) {
    const int i = b * 256 + threadIdx.x;
    if (i < W1TROWS * NFEATC) {
      const int n = i / NFEATC, k = i - n * NFEATC;
      float v = 0.f;
      if (n < HD1C) v = W1[(size_t)k * HD1C + n];
      else if (n < HD1C + NBASEC) v = B1[(size_t)k * NBASEC + (n - HD1C)];
      W1T[i] = f2bf(v);
    }
    return;
  }
  b -= W1T_NB;
  if (b < W2T_NB) {
    const int i = b * 256 + threadIdx.x;
    if (i < W2TROWS * HD1C) {
      const int n = i / HD1C, k = i - n * HD1C;
      float v = 0.f;
      if (n < NCLASSC) v = W2[(size_t)k * NCLASSC + n];
      else if (n < NCLASSC + NBASEC) v = B2[(size_t)k * NBASEC + (n - NCLASSC)];
      W2T[i] = f2bf(v);
    }
    return;
  }
  b -= W2T_NB;
  {
    const int e = b * 256 + threadIdx.x;
    if (e < N_EDGESC) atomicAdd(&counts[dst[e]], 1);
  }
}

// ---------------- 3-phase parallel scan ----------------
#define SCAN_NB ((N_NODESC + 255) / 256)   // 196

__global__ void reduce_counts(const int* __restrict__ counts, int* __restrict__ bsums) {
  __shared__ int sm[256];
  const int i = blockIdx.x * 256 + threadIdx.x;
  sm[threadIdx.x] = (i < N_NODESC) ? counts[i] : 0;
  __syncthreads();
  for (int d = 128; d > 0; d >>= 1) {
    if (threadIdx.x < (unsigned)d) sm[threadIdx.x] += sm[threadIdx.x + d];
    __syncthreads();
  }
  if (threadIdx.x == 0) bsums[blockIdx.x] = sm[0];
}

__global__ void scan_bsums_k(int* __restrict__ bsums) {
  __shared__ int sm[256];
  const int v = (threadIdx.x < SCAN_NB) ? bsums[threadIdx.x] : 0;
  sm[threadIdx.x] = v;
  __syncthreads();
  for (int d = 1; d < 256; d <<= 1) {
    const int t = (threadIdx.x >= (unsigned)d) ? sm[threadIdx.x - d] : 0;
    __syncthreads();
    sm[threadIdx.x] += t;
    __syncthreads();
  }
  if (threadIdx.x < SCAN_NB) bsums[threadIdx.x] = sm[threadIdx.x] - v;  // exclusive
}

__global__ void scan_final(const int* __restrict__ counts, const int* __restrict__ bsums,
                           int* __restrict__ offsets) {
  __shared__ int sm[256];
  const int i = blockIdx.x * 256 + threadIdx.x;
  const int v = (i < N_NODESC) ? counts[i] : 0;
  sm[threadIdx.x] = v;
  __syncthreads();
  for (int d = 1; d < 256; d <<= 1) {
    const int t = (threadIdx.x >= (unsigned)d) ? sm[threadIdx.x - d] : 0;
    __syncthreads();
    sm[threadIdx.x] += t;
    __syncthreads();
  }
  if (i < N_NODESC) offsets[i] = bsums[blockIdx.x] + sm[threadIdx.x] - v;
  if (i == 0) offsets[N_NODESC] = N_EDGESC;
}

// -------- scatter + layer-1 edge-weight precompute: srcs_csr, w1[pos][h]=exp(leaky(e)) ----
__global__ void scatter_w1(const int* __restrict__ dst, const int* __restrict__ src,
                           const int* __restrict__ offsets, int* __restrict__ counts,
                           const float* __restrict__ esrc, const float* __restrict__ edst,
                           int* __restrict__ srcs_csr, float* __restrict__ w1) {
  const int e = blockIdx.x * blockDim.x + threadIdx.x;
  if (e >= N_EDGESC) return;
  const int n = dst[e];
  const int s = src[e];
  const int pos = offsets[n] + atomicSub(&counts[n], 1) - 1;
  srcs_csr[pos] = s;
  const float4 es = *reinterpret_cast<const float4*>(esrc + (size_t)s * NHEADC);
  const float4 ed = *reinterpret_cast<const float4*>(edst + (size_t)n * NHEADC);
  float4 w;
  float t;
  t = es.x + ed.x; t = t > 0.f ? t : 0.2f * t; w.x = __expf(t);
  t = es.y + ed.y; t = t > 0.f ? t : 0.2f * t; w.y = __expf(t);
  t = es.z + ed.z; t = t > 0.f ? t : 0.2f * t; w.z = __expf(t);
  t = es.w + ed.w; t = t > 0.f ? t : 0.2f * t; w.w = __expf(t);
  *reinterpret_cast<float4*>(w1 + (size_t)pos * NHEADC) = w;
}

// ---------- layer-1 aggregate: 2 edges/half-wave, 8-edge unroll for MLP --------
__global__ __launch_bounds__(256) void agg1_kernel(
    const unsigned short* __restrict__ h1b, const float* __restrict__ w1,
    const int* __restrict__ srcs, const int* __restrict__ offsets,
    const float* __restrict__ bias, unsigned short* __restrict__ hactb) {
  const int wv = threadIdx.x >> 6;
  const int lane = threadIdx.x & 63;
  const int n = blockIdx.x * 4 + wv;
  if (n >= N_NODESC) return;
  const int half = lane >> 5;
  const int l = lane & 31;
  const int h = l >> 3;
  const int beg = offsets[n], end = offsets[n + 1];

  float wsum = 0.f;
  float acc[8] = {0.f, 0.f, 0.f, 0.f, 0.f, 0.f, 0.f, 0.f};
  int i = beg;
  // 8 edges per iteration: 4 per half, all index/weight loads batched ahead of gathers
  for (; i + 8 <= end; i += 8) {
    const int e0 = i + half, e1 = i + 2 + half, e2 = i + 4 + half, e3 = i + 6 + half;
    const int s0 = srcs[e0], s1 = srcs[e1], s2 = srcs[e2], s3 = srcs[e3];
    const float a0 = w1[((unsigned)e0 << 2) + h];
    const float a1 = w1[((unsigned)e1 << 2) + h];
    const float a2 = w1[((unsigned)e2 << 2) + h];
    const float a3 = w1[((unsigned)e3 << 2) + h];
    const uint4 h0 = *reinterpret_cast<const uint4*>(h1b + ((unsigned)s0 << 8) + l * 8);
    const uint4 h1 = *reinterpret_cast<const uint4*>(h1b + ((unsigned)s1 << 8) + l * 8);
    const uint4 h2 = *reinterpret_cast<const uint4*>(h1b + ((unsigned)s2 << 8) + l * 8);
    const uint4 h3 = *reinterpret_cast<const uint4*>(h1b + ((unsigned)s3 << 8) + l * 8);
    wsum += (a0 + a1) + (a2 + a3);
    acc[0] += a0 * blo(h0.x) + a1 * blo(h1.x) + a2 * blo(h2.x) + a3 * blo(h3.x);
    acc[1] += a0 * bhi(h0.x) + a1 * bhi(h1.x) + a2 * bhi(h2.x) + a3 * bhi(h3.x);
    acc[2] += a0 * blo(h0.y) + a1 * blo(h1.y) + a2 * blo(h2.y) + a3 * blo(h3.y);
    acc[3] += a0 * bhi(h0.y) + a1 * bhi(h1.y) + a2 * bhi(h2.y) + a3 * bhi(h3.y);
    acc[4] += a0 * blo(h0.z) + a1 * blo(h1.z) + a2 * blo(h2.z) + a3 * blo(h3.z);
    acc[5] += a0 * bhi(h0.z) + a1 * bhi(h1.z) + a2 * bhi(h2.z) + a3 * bhi(h3.z);
    acc[6] += a0 * blo(h0.w) + a1 * blo(h1.w) + a2 * blo(h2.w) + a3 * blo(h3.w);
    acc[7] += a0 * bhi(h0.w) + a1 * bhi(h1.w) + a2 * bhi(h2.w) + a3 * bhi(h3.w);
  }
  for (; i < end; i += 2) {
    const int e = i + half;
    if (e < end) {
      const int s = srcs[e];
      const float a = w1[((unsigned)e << 2) + h];
      const uint4 hv = *reinterpret_cast<const uint4*>(h1b + ((unsigned)s << 8) + l * 8);
      wsum += a;
      acc[0] += a * blo(hv.x); acc[1] += a * bhi(hv.x);
      acc[2] += a * blo(hv.y); acc[3] += a * bhi(hv.y);
      acc[4] += a * blo(hv.z); acc[5] += a * bhi(hv.z);
      acc[6] += a * blo(hv.w); acc[7] += a * bhi(hv.w);
    }
  }
#pragma unroll
  for (int k = 0; k < 8; ++k) acc[k] += __shfl_xor(acc[k], 32);
  wsum += __shfl_xor(wsum, 32);
  if (half == 0) {
    const float inv = 1.f / (wsum + 1e-16f);
    const int f = l * 8;
    const float4 b0 = *reinterpret_cast<const float4*>(bias + f);
    const float4 b1 = *reinterpret_cast<const float4*>(bias + f + 4);
    float v0 = acc[0] * inv + b0.x; v0 = v0 > 0.f ? v0 : __expf(v0) - 1.f;
    float v1 = acc[1] * inv + b0.y; v1 = v1 > 0.f ? v1 : __expf(v1) - 1.f;
    float v2 = acc[2] * inv + b0.z; v2 = v2 > 0.f ? v2 : __expf(v2) - 1.f;
    float v3 = acc[3] * inv + b0.w; v3 = v3 > 0.f ? v3 : __expf(v3) - 1.f;
    float v4 = acc[4] * inv + b1.x; v4 = v4 > 0.f ? v4 : __expf(v4) - 1.f;
    float v5 = acc[5] * inv + b1.y; v5 = v5 > 0.f ? v5 : __expf(v5) - 1.f;
    float v6 = acc[6] * inv + b1.z; v6 = v6 > 0.f ? v6 : __expf(v6) - 1.f;
    float v7 = acc[7] * inv + b1.w; v7 = v7 > 0.f ? v7 : __expf(v7) - 1.f;
    uint4 st;
    st.x = (unsigned)f2bf(v0) | ((unsigned)f2bf(v1) << 16);
    st.y = (unsigned)f2bf(v2) | ((unsigned)f2bf(v3) << 16);
    st.z = (unsigned)f2bf(v4) | ((unsigned)f2bf(v5) << 16);
    st.w = (unsigned)f2bf(v6) | ((unsigned)f2bf(v7) << 16);
    *reinterpret_cast<uint4*>(hactb + ((unsigned)n << 8) + f) = st;
  }
}

// ---------- layer-2 aggregate: 3 edges/wave in 20-lane groups, 6-edge unroll --------
// lanes 0..59: group g = lane/20 owns one edge, lane-in-group gl covers classes 2gl,2gl+1.
// lanes 60..63 mirror group 0 (results discarded). Cross-group combine via shfl(lane+20/40).
__global__ __launch_bounds__(256) void agg2_kernel(
    const unsigned short* __restrict__ g2b, const float* __restrict__ esrc,
    const float* __restrict__ edst, const int* __restrict__ srcs,
    const int* __restrict__ offsets, float* __restrict__ out) {
  const int wv = threadIdx.x >> 6;
  const int lane = threadIdx.x & 63;
  const int n = blockIdx.x * 4 + wv;
  if (n >= N_NODESC) return;
  int g = lane / 20;
  int gl = lane - g * 20;
  if (g > 2) { g = 0; gl = 0; }   // lanes 60-63: duplicate lane 0's work (broadcast loads)
  const int beg = offsets[n], end = offsets[n + 1];
  const float ed = edst[n];

  float wsum = 0.f, acc0 = 0.f, acc1 = 0.f;
  int i = beg;
  for (; i + 6 <= end; i += 6) {
    const int eA = i + g, eB = i + 3 + g;
    const int sA = srcs[eA], sB = srcs[eB];
    float tA = esrc[sA] + ed;
    float tB = esrc[sB] + ed;
    const unsigned gA = *reinterpret_cast<const unsigned*>(g2b + (unsigned)sA * NCLASSC + gl * 2);
    const unsigned gB = *reinterpret_cast<const unsigned*>(g2b + (unsigned)sB * NCLASSC + gl * 2);
    tA = tA > 0.f ? tA : 0.2f * tA;
    tB = tB > 0.f ? tB : 0.2f * tB;
    const float aA = __expf(tA), aB = __expf(tB);
    wsum += aA + aB;
    acc0 += aA * blo(gA) + aB * blo(gB);
    acc1 += aA * bhi(gA) + aB * bhi(gB);
  }
  for (; i < end; i += 3) {
    const int e = i + g;
    if (e < end) {
      const int s = srcs[e];
      float t = esrc[s] + ed;
      const unsigned gv = *reinterpret_cast<const unsigned*>(g2b + (unsigned)s * NCLASSC + gl * 2);
      t = t > 0.f ? t : 0.2f * t;
      const float a = __expf(t);
      wsum += a;
      acc0 += a * blo(gv);
      acc1 += a * bhi(gv);
    }
  }
  // combine the 3 groups (lane<20 pulls from lane+20 and lane+40; others produce garbage, unused)
  const float p0 = __shfl(acc0, lane + 20), q0 = __shfl(acc0, lane + 40);
  const float p1 = __shfl(acc1, lane + 20), q1 = __shfl(acc1, lane + 40);
  const float pw = __shfl(wsum, lane + 20), qw = __shfl(wsum, lane + 40);
  acc0 += p0 + q0;
  acc1 += p1 + q1;
  wsum += pw + qw;
  if (lane < 20) {
    const float inv = 1.f / (wsum + 1e-16f);
    float2 o;
    o.x = acc0 * inv;
    o.y = acc1 * inv;
    *reinterpret_cast<float2*>(out + (size_t)n * NCLASSC + lane * 2) = o;
  }
}

extern "C" void kernel_launch(void* const* d_in, const int* in_sizes, int n_in,
                              void* d_out, int out_size, void* d_ws, size_t ws_size,
                              hipStream_t stream) {
  const float* x   = (const float*)d_in[0];
  const int*   ei  = (const int*)d_in[1];
  const float* W1  = (const float*)d_in[2];
  const float* b1  = (const float*)d_in[3];
  const float* B1  = (const float*)d_in[4];
  const float* cs1 = (const float*)d_in[5];
  const float* cd1 = (const float*)d_in[6];
  const float* W2  = (const float*)d_in[7];
  const float* B2  = (const float*)d_in[8];
  const float* cs2 = (const float*)d_in[9];
  const float* cd2 = (const float*)d_in[10];
  const int* srcA = ei;
  const int* dstA = ei + N_EDGESC;
  float* out = (float*)d_out;

  char* ws = (char*)d_ws;
  size_t off = 0;
  auto alloc = [&](size_t bytes) -> void* {
    void* p = ws + off;
    off += (bytes + 255) & ~(size_t)255;
    return p;
  };
  unsigned short* h1b   = (unsigned short*)alloc((size_t)N_NODESC * HD1C * 2);
  unsigned short* hactb = (unsigned short*)alloc((size_t)N_NODESC * HD1C * 2);
  unsigned short* g2b   = (unsigned short*)alloc((size_t)N_NODESC * NCLASSC * 2);
  unsigned short* W1T   = (unsigned short*)alloc((size_t)W1TROWS * NFEATC * 2);
  unsigned short* W2T   = (unsigned short*)alloc((size_t)W2TROWS * HD1C * 2);
  float* esrc1  = (float*)alloc((size_t)N_NODESC * NHEADC * 4);
  float* edst1  = (float*)alloc((size_t)N_NODESC * NHEADC * 4);
  float* esrc2  = (float*)alloc((size_t)N_NODESC * 4);
  float* edst2  = (float*)alloc((size_t)N_NODESC * 4);
  float* w1     = (float*)alloc((size_t)N_EDGESC * NHEADC * 4);
  int* counts   = (int*)alloc((size_t)N_NODESC * 4);
  int* offsets  = (int*)alloc((size_t)(N_NODESC + 1) * 4);
  int* bsums    = (int*)alloc((size_t)SCAN_NB * 4);
  int* srcs_csr = (int*)alloc((size_t)N_EDGESC * 4);

  hipMemsetAsync(counts, 0, (size_t)N_NODESC * 4, stream);

  // prep (W1T, W2T, dst histogram)
  prep_kernel<<<PREP_NB, 256, 0, stream>>>(W1, B1, W1T, W2, B2, W2T, dstA, counts);

  // layer-1 GEMM (+ attn scalars) -- needs only W1T
  gemm1_fused<<<(N_NODESC + 255) / 256, 256, 0, stream>>>(x, W1T, cs1, cd1, h1b, esrc1,
                                                          edst1);

  // CSR offsets (3-phase parallel scan) + scatter fused with layer-1 edge weights
  reduce_counts<<<SCAN_NB, 256, 0, stream>>>(counts, bsums);
  scan_bsums_k<<<1, 256, 0, stream>>>(bsums);
  scan_final<<<SCAN_NB, 256, 0, stream>>>(counts, bsums, offsets);
  scatter_w1<<<(N_EDGESC + 255) / 256, 256, 0, stream>>>(dstA, srcA, offsets, counts,
                                                         esrc1, edst1, srcs_csr, w1);

  agg1_kernel<<<(N_NODESC + 3) / 4, 256, 0, stream>>>(h1b, w1, srcs_csr, offsets, b1,
                                                      hactb);

  // layer 2
  gemm2_fused<<<(N_NODESC + 255) / 256, 256, 0, stream>>>(hactb, W2T, cs2, cd2, g2b, esrc2,
                                                          edst2);
  agg2_kernel<<<(N_NODESC + 3) / 4, 256, 0, stream>>>(g2b, esrc2, edst2, srcs_csr, offsets,
                                                      out);
}